// Round 11
// baseline (800.189 us; speedup 1.0000x reference)
//
#include <hip/hip_runtime.h>
#include <hip/hip_bf16.h>
#include <cstdint>
#include <cstddef>

#define S_LEN 2048
#define HID   4096
#define HD    128
#define NH    32
#define NKV   8
#define KVW   (NKV * HD)        /* 1024 */
#define QKVN  (HID + 2 * KVW)   /* 6144 */

typedef __bf16 bf16x8_t __attribute__((ext_vector_type(8)));
typedef float  f32x4_t  __attribute__((ext_vector_type(4)));
typedef unsigned short u16x8_t __attribute__((ext_vector_type(8)));

__device__ __forceinline__ unsigned short f2b(float f) {
  unsigned u = __float_as_uint(f);
  u += 0x7FFFu + ((u >> 16) & 1u);
  return (unsigned short)(u >> 16);
}
__device__ __forceinline__ float b2f(unsigned short v) {
  return __uint_as_float(((unsigned)v) << 16);
}
__device__ __forceinline__ void gld_lds16(const void* g, void* l) {
  __builtin_amdgcn_global_load_lds(
      (const __attribute__((address_space(1))) void*)g,
      (__attribute__((address_space(3))) void*)l, 16, 0, 0);
}

// ---------------- fp32 -> bf16 conversion ----------------
__global__ void cvt_kernel(const float* __restrict__ src,
                           unsigned short* __restrict__ dst, int n4) {
  int i = blockIdx.x * blockDim.x + threadIdx.x;
  int stride = gridDim.x * blockDim.x;
  for (; i < n4; i += stride) {
    float4 v = reinterpret_cast<const float4*>(src)[i];
    ushort4 o;
    o.x = f2b(v.x); o.y = f2b(v.y); o.z = f2b(v.z); o.w = f2b(v.w);
    reinterpret_cast<ushort4*>(dst)[i] = o;
  }
}

// ---------------- RoPE (in-place on bf16 Q and K) ----------------
__global__ void rope_kernel(unsigned short* __restrict__ Q,
                            unsigned short* __restrict__ Kb,
                            const int* __restrict__ pos_ids) {
  const int total = S_LEN * (NH + NKV) * 64;
  int idx = blockIdx.x * blockDim.x + threadIdx.x;
  int stride = gridDim.x * blockDim.x;
  for (; idx < total; idx += stride) {
    int s   = idx / ((NH + NKV) * 64);
    int rem = idx % ((NH + NKV) * 64);
    int hp  = rem >> 6;
    int i   = rem & 63;
    unsigned short* ptr; int W, h;
    if (hp < NH) { ptr = Q;  W = HID; h = hp; }
    else         { ptr = Kb; W = KVW; h = hp - NH; }
    float pos = (float)pos_ids[s];
    float ang = pos * __expf(-(float)i * 0.14391156516f); // ln(10000)/64
    float sn, cs;
    sincosf(ang, &sn, &cs);
    size_t base = (size_t)s * W + (size_t)h * HD + i;
    float lo = b2f(ptr[base]);
    float hi = b2f(ptr[base + 64]);
    ptr[base]      = f2b(lo * cs - hi * sn);
    ptr[base + 64] = f2b(hi * cs + lo * sn);
  }
}

// -------- B-direct pipelined GEMM, 2 blocks/CU: C = A(MxK)*B(NxK)^T --------
// r10 showed the GEMM is LDS-BW-bound (618KB/CU per 2 K-tiles = measured
// 7.1k cy). Fix: only A (the 4x-wave-amplified operand) goes through LDS;
// B fragments load DIRECT global->reg (per-wave need 6KB/tile; wm-pair waves
// share via L1 since B tile 24KB < 32KB L1). LDS/CU/K-tile drops to ~163KB.
// BM=128, BK=64, A double-buffered in LDS (2x16KB = 32KB/block, 2 blocks/CU).
// Per K-tile t: {8 ds_read A(t) | load B(t+1)->regs (T14)} -> 24 MFMA
// (compiler-interleaved lgkm waits) -> lgkmcnt(0)+barrier (all waves done
// reading buf t&1) -> stage A(t+2) DMA into buf t&1 -> vmcnt(2) -> barrier.
// vmcnt(2) ledger is reorder-robust: A(t+1)'s 2 DMAs are the OLDEST
// outstanding VMEM ops, so "<=2 outstanding" (the just-issued A(t+2)) proves
// A(t+1) landed wherever the compiler puts the B loads. B(t) regs were
// drained by tile t-1's vmcnt(2) (issued before stage A(t+1)).
// Swizzle byte^=(row&7)<<4 on A (both sides). 512 thr = 8 waves (2M x 4N);
// per-wave out 64 x BN/4. Grid (N/BN, M/128).
// MODE 1: fp32 out. MODE 2: QKV split w/ V transposed.
template <int BN, int MODE>
__global__ __launch_bounds__(512, 4) void gemmbd_kernel(
    const unsigned short* __restrict__ A, const unsigned short* __restrict__ B,
    void* __restrict__ C0, void* __restrict__ C1, void* __restrict__ C2,
    int N, int K) {
  constexpr int NFR = BN / 64;           // n-frags per wave (3 or 2)
  __shared__ char ldsA[2 * 16384];

  const int tid  = threadIdx.x;
  const int lane = tid & 63;
  const int wid  = tid >> 6;
  const int wm = wid >> 2, wn = wid & 3;
  const int lr = lane & 15, g = lane >> 4;
  const int bm = blockIdx.y * 128;
  const int bn = blockIdx.x * BN;
  const int nk = K >> 6;
  const int xr = (lr & 7) << 4;

  // stage both 8KB units of A K-tile t into buf (t&1)
  auto stage_a = [&](int t) {
    const int riu = tid >> 3;                             // row in unit 0..63
    const int cbs = ((tid & 7) << 4) ^ ((riu & 7) << 4);  // pre-swizzled src col
#pragma unroll
    for (int u = 0; u < 2; ++u) {
      const char* src =
          (const char*)A + ((size_t)(bm + u * 64 + riu) * K + t * 64) * 2 + cbs;
      gld_lds16(src, ldsA + (t & 1) * 16384 + u * 8192 + tid * 16);
    }
  };

  auto rdA = [&](int t, int m, int k) {
    const int row = wm * 64 + m * 16 + lr;
    return *(const bf16x8_t*)(ldsA + (t & 1) * 16384 + row * 128 +
                              ((k * 64 + g * 16) ^ xr));
  };

  // load B fragments of K-tile t direct from global into regs
#define LD_B(dst, t)                                                          \
  _Pragma("unroll") for (int n = 0; n < NFR; ++n)                             \
    _Pragma("unroll") for (int k = 0; k < 2; ++k)                             \
      dst[n][k] = *(const bf16x8_t*)(const void*)(                            \
          B + (size_t)(bn + wn * (BN / 4) + n * 16 + lr) * K + (t) * 64 +     \
          k * 32 + g * 8);

  // prologue: stage A(0), A(1); load B(0); drain; barrier
  stage_a(0);
  if (nk > 1) stage_a(1);
  bf16x8_t brE[NFR][2], brO[NFR][2];
  LD_B(brE, 0);
  asm volatile("s_waitcnt vmcnt(0)" ::: "memory");
  __builtin_amdgcn_sched_barrier(0);
  __builtin_amdgcn_s_barrier();

  f32x4_t acc[4][NFR];
#pragma unroll
  for (int m = 0; m < 4; ++m)
#pragma unroll
    for (int n = 0; n < NFR; ++n) acc[m][n] = f32x4_t{0.f, 0.f, 0.f, 0.f};

  bf16x8_t af[4][2];

#define TILE(T, BCUR, BNXT)                                                   \
  {                                                                           \
    const int t = (T);                                                        \
    _Pragma("unroll") for (int m = 0; m < 4; ++m)                             \
      _Pragma("unroll") for (int k = 0; k < 2; ++k)                           \
        af[m][k] = rdA(t, m, k);                                              \
    if (t + 1 < nk) { LD_B(BNXT, t + 1); }                                    \
    __builtin_amdgcn_s_setprio(1);                                            \
    _Pragma("unroll") for (int m = 0; m < 4; ++m)                             \
      _Pragma("unroll") for (int n = 0; n < NFR; ++n)                         \
        _Pragma("unroll") for (int k = 0; k < 2; ++k)                         \
          acc[m][n] = __builtin_amdgcn_mfma_f32_16x16x32_bf16(                \
              af[m][k], BCUR[n][k], acc[m][n], 0, 0, 0);                      \
    __builtin_amdgcn_s_setprio(0);                                            \
    asm volatile("s_waitcnt lgkmcnt(0)" ::: "memory");                        \
    __builtin_amdgcn_sched_barrier(0);                                        \
    __builtin_amdgcn_s_barrier();                                             \
    if (t + 2 < nk) stage_a(t + 2);                                           \
    if (t + 1 < nk) {                                                         \
      asm volatile("s_waitcnt vmcnt(2)" ::: "memory");                        \
    }                                                                         \
    __builtin_amdgcn_sched_barrier(0);                                        \
    __builtin_amdgcn_s_barrier();                                             \
  }

  for (int i = 0; i < (nk >> 1); ++i) {
    TILE(2 * i,     brE, brO);
    TILE(2 * i + 1, brO, brE);
  }
#undef TILE
#undef LD_B

  // ---- epilogue ----
#pragma unroll
  for (int mf = 0; mf < 4; ++mf) {
    const int row0 = bm + wm * 64 + mf * 16 + g * 4;
#pragma unroll
    for (int nf = 0; nf < NFR; ++nf) {
      const int col = bn + wn * (BN / 4) + nf * 16 + lr;
      if constexpr (MODE == 1) {
#pragma unroll
        for (int r = 0; r < 4; ++r)
          ((float*)C0)[(size_t)(row0 + r) * N + col] = acc[mf][nf][r];
      } else {
        if (col < HID) {
#pragma unroll
          for (int r = 0; r < 4; ++r)
            ((unsigned short*)C0)[(size_t)(row0 + r) * HID + col] = f2b(acc[mf][nf][r]);
        } else if (col < HID + KVW) {
#pragma unroll
          for (int r = 0; r < 4; ++r)
            ((unsigned short*)C1)[(size_t)(row0 + r) * KVW + (col - HID)] = f2b(acc[mf][nf][r]);
        } else {
          const int c2 = col - HID - KVW;
          ushort4 w;
          w.x = f2b(acc[mf][nf][0]); w.y = f2b(acc[mf][nf][1]);
          w.z = f2b(acc[mf][nf][2]); w.w = f2b(acc[mf][nf][3]);
          *(ushort4*)(void*)&((unsigned short*)C2)[(size_t)c2 * S_LEN + row0] = w;
        }
      }
    }
  }
}

// ---------------- flash attention v3 (causal, GQA 4:1) ----------------
__global__ __launch_bounds__(256) void attn_kernel(
    const unsigned short* __restrict__ Q, const unsigned short* __restrict__ K,
    const unsigned short* __restrict__ VtG, unsigned short* __restrict__ O) {
  __shared__ unsigned short Kl[64][136];
  __shared__ unsigned short Vt[128][72];
  __shared__ unsigned short Pl[4][16][72];

  const int tid  = threadIdx.x;
  const int lane = tid & 63;
  const int wave = tid >> 6;
  const int h    = blockIdx.y;
  const int kvh  = h >> 2;
  const int pair = blockIdx.x;             // [0,16)
  const int lr   = lane & 15;
  const int g    = lane >> 4;
  const int lk8  = g * 8;
  const float scale = 0.08838834764831845f;  // 1/sqrt(128)
  const unsigned short* Vbase = VtG + (size_t)kvh * HD * S_LEN;

  const int ksr = tid >> 4, ksc = (tid & 15) * 8;
  const int vsr = tid >> 3, vsc = (tid & 7) * 8;

  for (int pass = 0; pass < 2; ++pass) {
    const int qb = pass == 0 ? (31 - pair) : pair;
    const int q0 = qb * 64;
    const int qrow = q0 + wave * 16;
    const int nkv = qb + 1;

    bf16x8_t qf[4];
    {
      const unsigned short* qp = Q + (size_t)(qrow + lr) * HID + (size_t)h * HD;
#pragma unroll
      for (int c = 0; c < 4; ++c)
        qf[c] = *(const bf16x8_t*)(const void*)(qp + c * 32 + lk8);
    }
    f32x4_t oacc[8];
#pragma unroll
    for (int c = 0; c < 8; ++c) oacc[c] = f32x4_t{0.f, 0.f, 0.f, 0.f};
    float m_run = -3e38f, l_run = 0.f;

    u16x8_t kr[4], vr[4];
#pragma unroll
    for (int i = 0; i < 4; ++i)
      kr[i] = *(const u16x8_t*)(const void*)(K + (size_t)(ksr + i * 16) * KVW +
                                             (size_t)kvh * HD + ksc);
#pragma unroll
    for (int i = 0; i < 4; ++i)
      vr[i] = *(const u16x8_t*)(const void*)(Vbase + (size_t)(vsr + i * 32) * S_LEN + vsc);

    for (int it = 0; it < nkv; ++it) {
      const int kv0 = it * 64;
      __builtin_amdgcn_s_barrier();
#pragma unroll
      for (int i = 0; i < 4; ++i)
        *(u16x8_t*)(void*)&Kl[ksr + i * 16][ksc] = kr[i];
#pragma unroll
      for (int i = 0; i < 4; ++i)
        *(u16x8_t*)(void*)&Vt[vsr + i * 32][vsc] = vr[i];
      if (it + 1 < nkv) {
        const int kn = kv0 + 64;
#pragma unroll
        for (int i = 0; i < 4; ++i)
          kr[i] = *(const u16x8_t*)(const void*)(K + (size_t)(kn + ksr + i * 16) * KVW +
                                                 (size_t)kvh * HD + ksc);
#pragma unroll
        for (int i = 0; i < 4; ++i)
          vr[i] = *(const u16x8_t*)(const void*)(Vbase + (size_t)(vsr + i * 32) * S_LEN +
                                                 kn + vsc);
      }
      asm volatile("s_waitcnt lgkmcnt(0)" ::: "memory");
      __builtin_amdgcn_sched_barrier(0);
      __builtin_amdgcn_s_barrier();

      f32x4_t sacc[4];
#pragma unroll
      for (int n = 0; n < 4; ++n) sacc[n] = f32x4_t{0.f, 0.f, 0.f, 0.f};
#pragma unroll
      for (int c = 0; c < 4; ++c) {
        bf16x8_t qc = qf[c];
#pragma unroll
        for (int n = 0; n < 4; ++n) {
          bf16x8_t kf = *(const bf16x8_t*)(const void*)&Kl[n * 16 + lr][c * 32 + lk8];
          sacc[n] = __builtin_amdgcn_mfma_f32_16x16x32_bf16(kf, qc, sacc[n], 0, 0, 0);
        }
      }

      const int qg = qrow + lr;
      const bool diag = (it == nkv - 1);
      float p[16];
      float mloc = -3e38f;
#pragma unroll
      for (int n = 0; n < 4; ++n)
#pragma unroll
        for (int r = 0; r < 4; ++r) {
          float x = sacc[n][r] * scale;
          if (diag) {
            int kg = kv0 + n * 16 + g * 4 + r;
            if (kg > qg) x = -3e38f;
          }
          p[n * 4 + r] = x;
          mloc = fmaxf(mloc, x);
        }
      mloc = fmaxf(mloc, __shfl_xor(mloc, 16));
      mloc = fmaxf(mloc, __shfl_xor(mloc, 32));

      if (__any(mloc > m_run + 8.f)) {
        float m_new = fmaxf(m_run, mloc);
        float alpha = __expf(m_run - m_new);
        float a4[4];
#pragma unroll
        for (int r = 0; r < 4; ++r) a4[r] = __shfl(alpha, g * 4 + r);
#pragma unroll
        for (int c = 0; c < 8; ++c)
#pragma unroll
          for (int r = 0; r < 4; ++r) oacc[c][r] *= a4[r];
        l_run *= alpha;
        m_run = m_new;
      }

      float ssum = 0.f;
#pragma unroll
      for (int i = 0; i < 16; ++i) {
        float e = __expf(p[i] - m_run);
        p[i] = e;
        ssum += e;
      }
      ssum += __shfl_xor(ssum, 16);
      ssum += __shfl_xor(ssum, 32);
      l_run += ssum;

#pragma unroll
      for (int n = 0; n < 4; ++n) {
        ushort4 w;
        w.x = f2b(p[n * 4 + 0]); w.y = f2b(p[n * 4 + 1]);
        w.z = f2b(p[n * 4 + 2]); w.w = f2b(p[n * 4 + 3]);
        *(ushort4*)(void*)&Pl[wave][lr][n * 16 + g * 4] = w;
      }

#pragma unroll
      for (int half = 0; half < 2; ++half) {
        bf16x8_t pf = *(const bf16x8_t*)(const void*)&Pl[wave][lr][half * 32 + lk8];
#pragma unroll
        for (int c = 0; c < 8; ++c) {
          bf16x8_t vf = *(const bf16x8_t*)(const void*)&Vt[c * 16 + lr][half * 32 + lk8];
          oacc[c] = __builtin_amdgcn_mfma_f32_16x16x32_bf16(pf, vf, oacc[c], 0, 0, 0);
        }
      }
    }

    float linv[4];
#pragma unroll
    for (int r = 0; r < 4; ++r) linv[r] = 1.f / __shfl(l_run, g * 4 + r);
#pragma unroll
    for (int r = 0; r < 4; ++r) {
      int row = qrow + g * 4 + r;
#pragma unroll
      for (int c = 0; c < 8; ++c)
        O[(size_t)row * HID + (size_t)h * HD + c * 16 + lr] = f2b(oacc[c][r] * linv[r]);
    }
  }
}

// ---------------- host launch ----------------
extern "C" void kernel_launch(void* const* d_in, const int* in_sizes, int n_in,
                              void* d_out, int out_size, void* d_ws, size_t ws_size,
                              hipStream_t stream) {
  (void)in_sizes; (void)n_in; (void)out_size; (void)ws_size;
  const float* X  = (const float*)d_in[0];
  const float* Wq = (const float*)d_in[1];
  const float* Wk = (const float*)d_in[2];
  const float* Wv = (const float*)d_in[3];
  const float* Wo = (const float*)d_in[4];
  const int*  pos = (const int*)d_in[5];
  float* out = (float*)d_out;

  unsigned short* Xb  = (unsigned short*)d_ws;
  unsigned short* Wqb = Xb  + (size_t)S_LEN * HID;
  unsigned short* Wkb = Wqb + (size_t)HID * HID;    // contiguous with Wqb
  unsigned short* Wvb = Wkb + (size_t)KVW * HID;    // contiguous -> [6144 x 4096] B
  unsigned short* Wob = Wvb + (size_t)KVW * HID;
  unsigned short* Qb  = Wob + (size_t)HID * HID;
  unsigned short* Kb  = Qb  + (size_t)S_LEN * HID;
  unsigned short* VtB = Kb  + (size_t)S_LEN * KVW;  // V^T: [KVW][S_LEN]
  unsigned short* AOb = VtB + (size_t)S_LEN * KVW;

  auto cvt = [&](const float* s, unsigned short* d, size_t n) {
    int n4 = (int)(n / 4);
    int grid = (n4 + 255) / 256;
    if (grid > 4096) grid = 4096;
    cvt_kernel<<<grid, 256, 0, stream>>>(s, d, n4);
  };
  cvt(X,  Xb,  (size_t)S_LEN * HID);
  cvt(Wq, Wqb, (size_t)HID * HID);
  cvt(Wk, Wkb, (size_t)KVW * HID);
  cvt(Wv, Wvb, (size_t)KVW * HID);
  cvt(Wo, Wob, (size_t)HID * HID);

  // QKV projection: 128x192 tiles, grid 32x16 = 512 blocks (2 per CU)
  gemmbd_kernel<192, 2><<<dim3(QKVN / 192, S_LEN / 128), 512, 0, stream>>>(
      Xb, Wqb, Qb, Kb, VtB, QKVN, HID);

  rope_kernel<<<2048, 256, 0, stream>>>(Qb, Kb, pos);

  // folded-balance attention: 16 pair-blocks x 32 heads
  attn_kernel<<<dim3(16, NH), 256, 0, stream>>>(Qb, Kb, VtB, AOb);

  // output projection: 128x128 tiles, grid 32x16 = 512 blocks (2 per CU) -> fp32
  gemmbd_kernel<128, 1><<<dim3(HID / 128, S_LEN / 128), 512, 0, stream>>>(
      AOb, Wob, out, nullptr, nullptr, HID, HID);
}

// Round 12
// 293.178 us; speedup vs baseline: 2.7294x; 2.7294x over previous
//
#include <hip/hip_runtime.h>
#include <hip/hip_bf16.h>
#include <cstdint>
#include <cstddef>

#define S_LEN 2048
#define HID   4096
#define HD    128
#define NH    32
#define NKV   8
#define KVW   (NKV * HD)        /* 1024 */
#define QKVN  (HID + 2 * KVW)   /* 6144 */

typedef __bf16 bf16x8_t __attribute__((ext_vector_type(8)));
typedef float  f32x4_t  __attribute__((ext_vector_type(4)));
typedef unsigned short u16x8_t __attribute__((ext_vector_type(8)));

__device__ __forceinline__ unsigned short f2b(float f) {
  unsigned u = __float_as_uint(f);
  u += 0x7FFFu + ((u >> 16) & 1u);
  return (unsigned short)(u >> 16);
}
__device__ __forceinline__ float b2f(unsigned short v) {
  return __uint_as_float(((unsigned)v) << 16);
}
__device__ __forceinline__ void gld_lds16(const void* g, void* l) {
  __builtin_amdgcn_global_load_lds(
      (const __attribute__((address_space(1))) void*)g,
      (__attribute__((address_space(3))) void*)l, 16, 0, 0);
}

// ---------------- fp32 -> bf16 conversion ----------------
__global__ void cvt_kernel(const float* __restrict__ src,
                           unsigned short* __restrict__ dst, int n4) {
  int i = blockIdx.x * blockDim.x + threadIdx.x;
  int stride = gridDim.x * blockDim.x;
  for (; i < n4; i += stride) {
    float4 v = reinterpret_cast<const float4*>(src)[i];
    ushort4 o;
    o.x = f2b(v.x); o.y = f2b(v.y); o.z = f2b(v.z); o.w = f2b(v.w);
    reinterpret_cast<ushort4*>(dst)[i] = o;
  }
}

// ---------------- RoPE (in-place on bf16 Q and K) ----------------
__global__ void rope_kernel(unsigned short* __restrict__ Q,
                            unsigned short* __restrict__ Kb,
                            const int* __restrict__ pos_ids) {
  const int total = S_LEN * (NH + NKV) * 64;
  int idx = blockIdx.x * blockDim.x + threadIdx.x;
  int stride = gridDim.x * blockDim.x;
  for (; idx < total; idx += stride) {
    int s   = idx / ((NH + NKV) * 64);
    int rem = idx % ((NH + NKV) * 64);
    int hp  = rem >> 6;
    int i   = rem & 63;
    unsigned short* ptr; int W, h;
    if (hp < NH) { ptr = Q;  W = HID; h = hp; }
    else         { ptr = Kb; W = KVW; h = hp - NH; }
    float pos = (float)pos_ids[s];
    float ang = pos * __expf(-(float)i * 0.14391156516f); // ln(10000)/64
    float sn, cs;
    sincosf(ang, &sn, &cs);
    size_t base = (size_t)s * W + (size_t)h * HD + i;
    float lo = b2f(ptr[base]);
    float hi = b2f(ptr[base + 64]);
    ptr[base]      = f2b(lo * cs - hi * sn);
    ptr[base + 64] = f2b(hi * cs + lo * sn);
  }
}

// ------------- 4-phase pipelined GEMM, 2 blocks/CU (r10, proven) -------------
// BM=128, BK=64, 2 LDS buffers (tile parity). 2 blocks/CU give independent
// barrier domains -> pipe overlap. vmcnt(NFR) counted waits; swizzle
// byte^=(row&7)<<4 both sides. MfmaUtil 50%, 0 bank conflicts @ r10.
template <int BN, int MODE>
__global__ __launch_bounds__(512, 4) void gemm4p_kernel(
    const unsigned short* __restrict__ A, const unsigned short* __restrict__ B,
    void* __restrict__ C0, void* __restrict__ C1, void* __restrict__ C2,
    int N, int K) {
  constexpr int NFR = BN / 64;
  constexpr int ABYTES = 128 * 128;      // 16 KB
  constexpr int TILE_LDS = ABYTES + BN * 128;
  __shared__ char ldsB[2 * TILE_LDS];

  const int tid  = threadIdx.x;
  const int lane = tid & 63;
  const int wid  = tid >> 6;
  const int wm = wid >> 2, wn = wid & 3;
  const int lr = lane & 15, g = lane >> 4;
  const int bm = blockIdx.y * 128;
  const int bn = blockIdx.x * BN;
  const int nk = K >> 6;
  const int ni = nk >> 1;
  const int xr = (lr & 7) << 4;

  auto stage_u = [&](int t, int u) {
    if (t >= nk) return;
    const int riu = tid >> 3;
    const int cbs = ((tid & 7) << 4) ^ ((riu & 7) << 4);
    const char* src;
    if (u < 2)
      src = (const char*)A + ((size_t)(bm + u * 64 + riu) * K + t * 64) * 2 + cbs;
    else
      src = (const char*)B + ((size_t)(bn + (u - 2) * 64 + riu) * K + t * 64) * 2 + cbs;
    gld_lds16(src, ldsB + (t & 1) * TILE_LDS + u * 8192 + tid * 16);
  };

  auto rdA = [&](const char* bb, int m, int k) {
    const int row = wm * 64 + m * 16 + lr;
    return *(const bf16x8_t*)(bb + row * 128 + ((k * 64 + g * 16) ^ xr));
  };
  auto rdB = [&](const char* bb, int n, int k) {
    const int row = wn * (BN / 4) + n * 16 + lr;
    return *(const bf16x8_t*)(bb + ABYTES + row * 128 + ((k * 64 + g * 16) ^ xr));
  };

  for (int t = 0; t < 2; ++t)
    for (int u = 0; u < 2 + NFR; ++u) stage_u(t, u);
  asm volatile("s_waitcnt vmcnt(0)" ::: "memory");
  __builtin_amdgcn_sched_barrier(0);
  __builtin_amdgcn_s_barrier();

  f32x4_t acc[4][NFR];
#pragma unroll
  for (int m = 0; m < 4; ++m)
#pragma unroll
    for (int n = 0; n < NFR; ++n) acc[m][n] = f32x4_t{0.f, 0.f, 0.f, 0.f};

  bf16x8_t bfr[NFR][2], af[2][2];

#define MFMA_BLOCK(MB)                                                        \
  __builtin_amdgcn_s_setprio(1);                                              \
  _Pragma("unroll") for (int m = 0; m < 2; ++m)                               \
    _Pragma("unroll") for (int n = 0; n < NFR; ++n)                           \
      _Pragma("unroll") for (int k = 0; k < 2; ++k)                           \
        acc[(MB) + m][n] = __builtin_amdgcn_mfma_f32_16x16x32_bf16(           \
            af[m][k], bfr[n][k], acc[(MB) + m][n], 0, 0, 0);                  \
  __builtin_amdgcn_s_setprio(0);

#define GATE()                                                                \
  __builtin_amdgcn_s_barrier();                                               \
  asm volatile("s_waitcnt lgkmcnt(0)" ::: "memory");                          \
  __builtin_amdgcn_sched_barrier(0);

#define RD_A2(bb, m0)                                                         \
  _Pragma("unroll") for (int m = 0; m < 2; ++m)                               \
    _Pragma("unroll") for (int k = 0; k < 2; ++k)                             \
      af[m][k] = rdA(bb, (m0) + m, k);

#define RD_B(bb)                                                              \
  _Pragma("unroll") for (int n = 0; n < NFR; ++n)                             \
    _Pragma("unroll") for (int k = 0; k < 2; ++k)                             \
      bfr[n][k] = rdB(bb, n, k);

  for (int i = 0; i < ni; ++i) {
    const char* bE = ldsB;
    const char* bO = ldsB + TILE_LDS;
    const int tO = 2 * i + 1, tE2 = 2 * i + 2, tO2 = 2 * i + 3;
    const bool last = (i == ni - 1);

    RD_B(bE);
    RD_A2(bE, 0);
    if (i > 0) { stage_u(tO, 0); stage_u(tO, 1); }
    GATE(); MFMA_BLOCK(0);
    __builtin_amdgcn_s_barrier();

    RD_A2(bE, 2);
#pragma unroll
    for (int u = 0; u < NFR; ++u) stage_u(tE2, 2 + u);
    GATE(); MFMA_BLOCK(2);
    if (last) { asm volatile("s_waitcnt vmcnt(0)" ::: "memory"); }
    else      { asm volatile("s_waitcnt vmcnt(%0)" :: "n"(NFR) : "memory"); }
    __builtin_amdgcn_sched_barrier(0);
    __builtin_amdgcn_s_barrier();

    RD_B(bO);
    RD_A2(bO, 0);
    stage_u(tE2, 0); stage_u(tE2, 1);
    GATE(); MFMA_BLOCK(0);
    __builtin_amdgcn_s_barrier();

    RD_A2(bO, 2);
#pragma unroll
    for (int u = 0; u < NFR; ++u) stage_u(tO2, 2 + u);
    GATE(); MFMA_BLOCK(2);
    if (!last) { asm volatile("s_waitcnt vmcnt(%0)" :: "n"(NFR) : "memory"); }
    __builtin_amdgcn_sched_barrier(0);
    __builtin_amdgcn_s_barrier();
  }
#undef MFMA_BLOCK
#undef GATE
#undef RD_A2
#undef RD_B

#pragma unroll
  for (int mf = 0; mf < 4; ++mf) {
    const int row0 = bm + wm * 64 + mf * 16 + g * 4;
#pragma unroll
    for (int nf = 0; nf < NFR; ++nf) {
      const int col = bn + wn * (BN / 4) + nf * 16 + lr;
      if constexpr (MODE == 1) {
#pragma unroll
        for (int r = 0; r < 4; ++r)
          ((float*)C0)[(size_t)(row0 + r) * N + col] = acc[mf][nf][r];
      } else {
        if (col < HID) {
#pragma unroll
          for (int r = 0; r < 4; ++r)
            ((unsigned short*)C0)[(size_t)(row0 + r) * HID + col] = f2b(acc[mf][nf][r]);
        } else if (col < HID + KVW) {
#pragma unroll
          for (int r = 0; r < 4; ++r)
            ((unsigned short*)C1)[(size_t)(row0 + r) * KVW + (col - HID)] = f2b(acc[mf][nf][r]);
        } else {
          const int c2 = col - HID - KVW;
          ushort4 w;
          w.x = f2b(acc[mf][nf][0]); w.y = f2b(acc[mf][nf][1]);
          w.z = f2b(acc[mf][nf][2]); w.w = f2b(acc[mf][nf][3]);
          *(ushort4*)(void*)&((unsigned short*)C2)[(size_t)c2 * S_LEN + row0] = w;
        }
      }
    }
  }
}

// ---------------- flash attention v4 (causal, GQA 4:1) ----------------
// DMA-staged, double-buffered K/V, ONE barrier per tile.
// K tile 64x256B: swizzle chunk ^= (row&15); V^T tile 128x128B: chunk ^= (row&7).
// Both applied as pre-swizzled GLOBAL source (linear LDS dest for
// global_load_lds) + same XOR on ds_read (rule #21). Tile t+1's 8 DMAs issue
// at tile-t start and drain (vmcnt 0) at tile end - hidden under compute.
// LDS: 2x16KB K + 2x16KB V + 9.2KB P = 73.2KB -> 2 blocks/CU.
// Folded pairing: block pair p does q-blocks {31-p, p} (33 tiles const).
__global__ __launch_bounds__(256) void attn_kernel(
    const unsigned short* __restrict__ Q, const unsigned short* __restrict__ K,
    const unsigned short* __restrict__ VtG, unsigned short* __restrict__ O) {
  __shared__ char KlB[2][16384];
  __shared__ char VtB2[2][16384];
  __shared__ unsigned short Pl[4][16][72];

  const int tid  = threadIdx.x;
  const int lane = tid & 63;
  const int wave = tid >> 6;
  const int h    = blockIdx.y;
  const int kvh  = h >> 2;
  const int pair = blockIdx.x;             // [0,16)
  const int lr   = lane & 15;
  const int g    = lane >> 4;
  const int lk8  = g * 8;
  const float scale = 0.08838834764831845f;  // 1/sqrt(128)

  // stage K tile (64 rows x 256B) into buf: 4 issues, 16 rows each
  auto stageK = [&](int kv0, int buf) {
#pragma unroll
    for (int j = 0; j < 4; ++j) {
      const int row  = j * 16 + (tid >> 4);
      const int colb = ((tid & 15) << 4) ^ ((row & 15) << 4);
      const char* src =
          (const char*)(K + (size_t)(kv0 + row) * KVW + (size_t)kvh * HD) + colb;
      gld_lds16(src, &KlB[buf][row * 256 + ((tid & 15) << 4)]);
    }
  };
  // stage V^T tile (128 rows x 128B) into buf: 4 issues, 32 rows each
  auto stageV = [&](int kv0, int buf) {
#pragma unroll
    for (int j = 0; j < 4; ++j) {
      const int row  = j * 32 + (tid >> 3);
      const int colb = ((tid & 7) << 4) ^ ((row & 7) << 4);
      const char* src =
          (const char*)(VtG + ((size_t)kvh * HD + row) * S_LEN + kv0) + colb;
      gld_lds16(src, &VtB2[buf][row * 128 + ((tid & 7) << 4)]);
    }
  };
  auto rdK = [&](int buf, int n, int c) {
    const int row = n * 16 + lr;
    return *(const bf16x8_t*)&KlB[buf][row * 256 +
                                       ((c * 64 + g * 16) ^ ((lr & 15) << 4))];
  };
  auto rdV = [&](int buf, int c, int half) {
    const int row = c * 16 + lr;
    return *(const bf16x8_t*)&VtB2[buf][row * 128 +
                                        ((half * 64 + g * 16) ^ ((lr & 7) << 4))];
  };

  for (int pass = 0; pass < 2; ++pass) {
    const int qb = pass == 0 ? (31 - pair) : pair;
    const int q0 = qb * 64;
    const int qrow = q0 + wave * 16;
    const int nkv = qb + 1;

    bf16x8_t qf[4];
    {
      const unsigned short* qp = Q + (size_t)(qrow + lr) * HID + (size_t)h * HD;
#pragma unroll
      for (int c = 0; c < 4; ++c)
        qf[c] = *(const bf16x8_t*)(const void*)(qp + c * 32 + lk8);
    }
    f32x4_t oacc[8];
#pragma unroll
    for (int c = 0; c < 8; ++c) oacc[c] = f32x4_t{0.f, 0.f, 0.f, 0.f};
    float m_run = -3e38f, l_run = 0.f;

    // prologue: stage tile 0 into buf 0; drain; barrier
    stageK(0, 0); stageV(0, 0);
    asm volatile("s_waitcnt vmcnt(0)" ::: "memory");
    __builtin_amdgcn_sched_barrier(0);
    __builtin_amdgcn_s_barrier();

    for (int it = 0; it < nkv; ++it) {
      const int kv0 = it * 64;
      const int buf = it & 1;
      // issue next tile's DMAs (target buf^1: read-complete since end of it-1)
      if (it + 1 < nkv) { stageK(kv0 + 64, buf ^ 1); stageV(kv0 + 64, buf ^ 1); }

      // ---- S^T = K * Q^T : acc col = q (lane&15), row = k (g*4+r + 16n) ----
      f32x4_t sacc[4];
#pragma unroll
      for (int n = 0; n < 4; ++n) sacc[n] = f32x4_t{0.f, 0.f, 0.f, 0.f};
#pragma unroll
      for (int c = 0; c < 4; ++c) {
        bf16x8_t qc = qf[c];
#pragma unroll
        for (int n = 0; n < 4; ++n)
          sacc[n] = __builtin_amdgcn_mfma_f32_16x16x32_bf16(rdK(buf, n, c), qc,
                                                            sacc[n], 0, 0, 0);
      }

      // ---- softmax over k (register-local 16 + 2 shfl) ----
      const int qg = qrow + lr;
      const bool diag = (it == nkv - 1);
      float p[16];
      float mloc = -3e38f;
#pragma unroll
      for (int n = 0; n < 4; ++n)
#pragma unroll
        for (int r = 0; r < 4; ++r) {
          float x = sacc[n][r] * scale;
          if (diag) {
            int kg = kv0 + n * 16 + g * 4 + r;
            if (kg > qg) x = -3e38f;
          }
          p[n * 4 + r] = x;
          mloc = fmaxf(mloc, x);
        }
      mloc = fmaxf(mloc, __shfl_xor(mloc, 16));
      mloc = fmaxf(mloc, __shfl_xor(mloc, 32));

      if (__any(mloc > m_run + 8.f)) {          // T13 deferred rescale
        float m_new = fmaxf(m_run, mloc);
        float alpha = __expf(m_run - m_new);
        float a4[4];
#pragma unroll
        for (int r = 0; r < 4; ++r) a4[r] = __shfl(alpha, g * 4 + r);
#pragma unroll
        for (int c = 0; c < 8; ++c)
#pragma unroll
          for (int r = 0; r < 4; ++r) oacc[c][r] *= a4[r];
        l_run *= alpha;
        m_run = m_new;
      }

      float ssum = 0.f;
#pragma unroll
      for (int i = 0; i < 16; ++i) {
        float e = __expf(p[i] - m_run);
        p[i] = e;
        ssum += e;
      }
      ssum += __shfl_xor(ssum, 16);
      ssum += __shfl_xor(ssum, 32);
      l_run += ssum;

      // ---- store P (transpose S^T -> row-major P[q][k]), wave-local ----
#pragma unroll
      for (int n = 0; n < 4; ++n) {
        ushort4 w;
        w.x = f2b(p[n * 4 + 0]); w.y = f2b(p[n * 4 + 1]);
        w.z = f2b(p[n * 4 + 2]); w.w = f2b(p[n * 4 + 3]);
        *(ushort4*)(void*)&Pl[wave][lr][n * 16 + g * 4] = w;
      }

      // ---- PV: out += P * V ----
#pragma unroll
      for (int half = 0; half < 2; ++half) {
        bf16x8_t pf = *(const bf16x8_t*)(const void*)&Pl[wave][lr][half * 32 + lk8];
#pragma unroll
        for (int c = 0; c < 8; ++c)
          oacc[c] = __builtin_amdgcn_mfma_f32_16x16x32_bf16(pf, rdV(buf, c, half),
                                                            oacc[c], 0, 0, 0);
      }

      // ---- tile end: next tile's DMAs landed; one barrier ----
      if (it + 1 < nkv) { asm volatile("s_waitcnt vmcnt(0)" ::: "memory"); }
      __builtin_amdgcn_sched_barrier(0);
      __builtin_amdgcn_s_barrier();
    }

    // ---- epilogue for this pass ----
    float linv[4];
#pragma unroll
    for (int r = 0; r < 4; ++r) linv[r] = 1.f / __shfl(l_run, g * 4 + r);
#pragma unroll
    for (int r = 0; r < 4; ++r) {
      int row = qrow + g * 4 + r;
#pragma unroll
      for (int c = 0; c < 8; ++c)
        O[(size_t)row * HID + (size_t)h * HD + c * 16 + lr] = f2b(oacc[c][r] * linv[r]);
    }
  }
}

// ---------------- host launch ----------------
extern "C" void kernel_launch(void* const* d_in, const int* in_sizes, int n_in,
                              void* d_out, int out_size, void* d_ws, size_t ws_size,
                              hipStream_t stream) {
  (void)in_sizes; (void)n_in; (void)out_size; (void)ws_size;
  const float* X  = (const float*)d_in[0];
  const float* Wq = (const float*)d_in[1];
  const float* Wk = (const float*)d_in[2];
  const float* Wv = (const float*)d_in[3];
  const float* Wo = (const float*)d_in[4];
  const int*  pos = (const int*)d_in[5];
  float* out = (float*)d_out;

  unsigned short* Xb  = (unsigned short*)d_ws;
  unsigned short* Wqb = Xb  + (size_t)S_LEN * HID;
  unsigned short* Wkb = Wqb + (size_t)HID * HID;    // contiguous with Wqb
  unsigned short* Wvb = Wkb + (size_t)KVW * HID;    // contiguous -> [6144 x 4096] B
  unsigned short* Wob = Wvb + (size_t)KVW * HID;
  unsigned short* Qb  = Wob + (size_t)HID * HID;
  unsigned short* Kb  = Qb  + (size_t)S_LEN * HID;
  unsigned short* VtB = Kb  + (size_t)S_LEN * KVW;  // V^T: [KVW][S_LEN]
  unsigned short* AOb = VtB + (size_t)S_LEN * KVW;

  auto cvt = [&](const float* s, unsigned short* d, size_t n) {
    int n4 = (int)(n / 4);
    int grid = (n4 + 255) / 256;
    if (grid > 4096) grid = 4096;
    cvt_kernel<<<grid, 256, 0, stream>>>(s, d, n4);
  };
  cvt(X,  Xb,  (size_t)S_LEN * HID);
  cvt(Wq, Wqb, (size_t)HID * HID);
  cvt(Wk, Wkb, (size_t)KVW * HID);
  cvt(Wv, Wvb, (size_t)KVW * HID);
  cvt(Wo, Wob, (size_t)HID * HID);

  // QKV projection: 128x192 tiles, grid 32x16 = 512 blocks (2 per CU)
  gemm4p_kernel<192, 2><<<dim3(QKVN / 192, S_LEN / 128), 512, 0, stream>>>(
      Xb, Wqb, Qb, Kb, VtB, QKVN, HID);

  rope_kernel<<<2048, 256, 0, stream>>>(Qb, Kb, pos);

  // folded-balance attention: 16 pair-blocks x 32 heads
  attn_kernel<<<dim3(16, NH), 256, 0, stream>>>(Qb, Kb, VtB, AOb);

  // output projection: 128x128 tiles, grid 32x16 = 512 blocks (2 per CU) -> fp32
  gemm4p_kernel<128, 1><<<dim3(HID / 128, S_LEN / 128), 512, 0, stream>>>(
      AOb, Wob, out, nullptr, nullptr, HID, HID);
}

// Round 13
// 282.958 us; speedup vs baseline: 2.8279x; 1.0361x over previous
//
#include <hip/hip_runtime.h>
#include <hip/hip_bf16.h>
#include <cstdint>
#include <cstddef>

#define S_LEN 2048
#define HID   4096
#define HD    128
#define NH    32
#define NKV   8
#define KVW   (NKV * HD)        /* 1024 */
#define QKVN  (HID + 2 * KVW)   /* 6144 */

typedef __bf16 bf16x8_t __attribute__((ext_vector_type(8)));
typedef float  f32x4_t  __attribute__((ext_vector_type(4)));
typedef unsigned short u16x8_t __attribute__((ext_vector_type(8)));

__device__ __forceinline__ unsigned short f2b(float f) {
  unsigned u = __float_as_uint(f);
  u += 0x7FFFu + ((u >> 16) & 1u);
  return (unsigned short)(u >> 16);
}
__device__ __forceinline__ float b2f(unsigned short v) {
  return __uint_as_float(((unsigned)v) << 16);
}
__device__ __forceinline__ void gld_lds16(const void* g, void* l) {
  __builtin_amdgcn_global_load_lds(
      (const __attribute__((address_space(1))) void*)g,
      (__attribute__((address_space(3))) void*)l, 16, 0, 0);
}

// ---------------- fp32 -> bf16 conversion ----------------
__global__ void cvt_kernel(const float* __restrict__ src,
                           unsigned short* __restrict__ dst, int n4) {
  int i = blockIdx.x * blockDim.x + threadIdx.x;
  int stride = gridDim.x * blockDim.x;
  for (; i < n4; i += stride) {
    float4 v = reinterpret_cast<const float4*>(src)[i];
    ushort4 o;
    o.x = f2b(v.x); o.y = f2b(v.y); o.z = f2b(v.z); o.w = f2b(v.w);
    reinterpret_cast<ushort4*>(dst)[i] = o;
  }
}

// ---------------- RoPE (in-place on bf16 Q and K) ----------------
__global__ void rope_kernel(unsigned short* __restrict__ Q,
                            unsigned short* __restrict__ Kb,
                            const int* __restrict__ pos_ids) {
  const int total = S_LEN * (NH + NKV) * 64;
  int idx = blockIdx.x * blockDim.x + threadIdx.x;
  int stride = gridDim.x * blockDim.x;
  for (; idx < total; idx += stride) {
    int s   = idx / ((NH + NKV) * 64);
    int rem = idx % ((NH + NKV) * 64);
    int hp  = rem >> 6;
    int i   = rem & 63;
    unsigned short* ptr; int W, h;
    if (hp < NH) { ptr = Q;  W = HID; h = hp; }
    else         { ptr = Kb; W = KVW; h = hp - NH; }
    float pos = (float)pos_ids[s];
    float ang = pos * __expf(-(float)i * 0.14391156516f); // ln(10000)/64
    float sn, cs;
    sincosf(ang, &sn, &cs);
    size_t base = (size_t)s * W + (size_t)h * HD + i;
    float lo = b2f(ptr[base]);
    float hi = b2f(ptr[base + 64]);
    ptr[base]      = f2b(lo * cs - hi * sn);
    ptr[base + 64] = f2b(hi * cs + lo * sn);
  }
}

// ---- 4-wave 4-phase pipelined GEMM, 2 blocks/CU: C = A(MxK)*B(NxK)^T ----
// r12 measured both GEMMs AT the LDS-BW model: time = LDS bytes / 85 B/cy/CU.
// Lever: LDS bytes/FLOP = n_g/BN + m_g/BM. 4 waves in 2x2 (vs 8 in 2x4)
// halves cross-wave amplification: QKV 0.0365->0.026, OP 0.0469->0.031 B/FLOP.
// BM=128, BK=64, 2 LDS buffers (tile parity), TILE = 16KB + BN*128 (40/32KB),
// 2 blocks/CU (160KB QKV / 128KB OP). Per-wave out 64 x BN/2; acc 4 x NFRW.
// Stage unit = 4KB (256thr x 16B) = 32 rows x 128B. A units u0..3, B u4..4+BU.
// 4 phases / 2 K-tiles (E=even buf, O=odd):
//  p1{rdB(E) + rdA(E,m0,1) | stage A(tO) u0-3}  p2{rdA(E,m2,3) | stage B(tE2),
//  vmcnt(BU)}  p3{rdB(O) + rdA(O,m0,1) | stage A(tE2)}  p4{rdA(O,m2,3) |
//  stage B(tO2), vmcnt(BU)}.  Ledger: p2's vmcnt(BU) leaves only B(tE2) ->
//  B(tO)[prev p4] + A(tO)[p1] drained = tile O confirmed; p4's leaves only
//  B(tO2) -> tile E2 confirmed. WAR: buf-O reads drained at prev-p4 GATE
//  (before its barrier) -> p1's A(tO) stage safe; buf-E reads drained at p2
//  GATE -> p3's A(tE2) stage safe. Last iter: p2 drains vmcnt(0), p4 skips.
// Swizzle byte^=(row&7)<<4 both sides (pre-swizzled global src + XOR reads).
// Regs: acc 96 + bfr 48 + af 16 ~ 190 < 256 (launch_bounds(256,2) -> 256 cap
// under either 2nd-arg semantics; r11's spill trap audited).
// MODE 1: fp32 out. MODE 2: QKV split w/ V transposed.
template <int BN, int MODE>
__global__ __launch_bounds__(256, 2) void gemm4w_kernel(
    const unsigned short* __restrict__ A, const unsigned short* __restrict__ B,
    void* __restrict__ C0, void* __restrict__ C1, void* __restrict__ C2,
    int N, int K) {
  constexpr int NFRW = BN / 32;          // n-frags per wave == B 4KB-units (6 or 4)
  constexpr int ABYTES = 128 * 128;      // 16 KB
  constexpr int TILE_LDS = ABYTES + BN * 128;
  __shared__ char ldsB[2 * TILE_LDS];

  const int tid  = threadIdx.x;
  const int lane = tid & 63;
  const int wid  = tid >> 6;             // 0..3
  const int wm = wid >> 1, wn = wid & 1;
  const int lr = lane & 15, g = lane >> 4;
  const int bm = blockIdx.y * 128;
  const int bn = blockIdx.x * BN;
  const int nk = K >> 6;
  const int ni = nk >> 1;
  const int xr = (lr & 7) << 4;

  // stage 4KB unit u of K-tile t into buf (t&1). u<4: A rows u*32..; else B.
  auto stage_u = [&](int t, int u) {
    if (t >= nk) return;
    const int riu = tid >> 3;            // 0..31
    const int cbs = ((tid & 7) << 4) ^ ((riu & 7) << 4);
    const char* src;
    if (u < 4)
      src = (const char*)A + ((size_t)(bm + u * 32 + riu) * K + t * 64) * 2 + cbs;
    else
      src = (const char*)B + ((size_t)(bn + (u - 4) * 32 + riu) * K + t * 64) * 2 + cbs;
    gld_lds16(src, ldsB + (t & 1) * TILE_LDS + u * 4096 + tid * 16);
  };

  auto rdA = [&](const char* bb, int m, int k) {
    const int row = wm * 64 + m * 16 + lr;
    return *(const bf16x8_t*)(bb + row * 128 + ((k * 64 + g * 16) ^ xr));
  };
  auto rdB = [&](const char* bb, int n, int k) {
    const int row = wn * (BN / 2) + n * 16 + lr;
    return *(const bf16x8_t*)(bb + ABYTES + row * 128 + ((k * 64 + g * 16) ^ xr));
  };

  // prologue: stage tiles 0,1 fully; drain; barrier
  for (int t = 0; t < 2; ++t)
    for (int u = 0; u < 4 + NFRW; ++u) stage_u(t, u);
  asm volatile("s_waitcnt vmcnt(0)" ::: "memory");
  __builtin_amdgcn_sched_barrier(0);
  __builtin_amdgcn_s_barrier();

  f32x4_t acc[4][NFRW];
#pragma unroll
  for (int m = 0; m < 4; ++m)
#pragma unroll
    for (int n = 0; n < NFRW; ++n) acc[m][n] = f32x4_t{0.f, 0.f, 0.f, 0.f};

  bf16x8_t bfr[NFRW][2], af[2][2];

#define MFMA_BLOCK(MB)                                                        \
  __builtin_amdgcn_s_setprio(1);                                              \
  _Pragma("unroll") for (int m = 0; m < 2; ++m)                               \
    _Pragma("unroll") for (int n = 0; n < NFRW; ++n)                          \
      _Pragma("unroll") for (int k = 0; k < 2; ++k)                           \
        acc[(MB) + m][n] = __builtin_amdgcn_mfma_f32_16x16x32_bf16(           \
            af[m][k], bfr[n][k], acc[(MB) + m][n], 0, 0, 0);                  \
  __builtin_amdgcn_s_setprio(0);

#define GATE()                                                                \
  __builtin_amdgcn_s_barrier();                                               \
  asm volatile("s_waitcnt lgkmcnt(0)" ::: "memory");                          \
  __builtin_amdgcn_sched_barrier(0);

#define RD_A2(bb, m0)                                                         \
  _Pragma("unroll") for (int m = 0; m < 2; ++m)                               \
    _Pragma("unroll") for (int k = 0; k < 2; ++k)                             \
      af[m][k] = rdA(bb, (m0) + m, k);

#define RD_B(bb)                                                              \
  _Pragma("unroll") for (int n = 0; n < NFRW; ++n)                            \
    _Pragma("unroll") for (int k = 0; k < 2; ++k)                             \
      bfr[n][k] = rdB(bb, n, k);

  for (int i = 0; i < ni; ++i) {
    const char* bE = ldsB;
    const char* bO = ldsB + TILE_LDS;
    const int tO = 2 * i + 1, tE2 = 2 * i + 2, tO2 = 2 * i + 3;
    const bool last = (i == ni - 1);

    // ---- p1: B(E) all + A(E) m0,1 | stage A(tO) ----
    RD_B(bE);
    RD_A2(bE, 0);
    if (i > 0) {
#pragma unroll
      for (int u = 0; u < 4; ++u) stage_u(tO, u);
    }
    GATE(); MFMA_BLOCK(0);
    __builtin_amdgcn_s_barrier();

    // ---- p2: A(E) m2,3 | stage B(tE2); confirm tile O ----
    RD_A2(bE, 2);
#pragma unroll
    for (int u = 0; u < NFRW; ++u) stage_u(tE2, 4 + u);
    GATE(); MFMA_BLOCK(2);
    if (last) { asm volatile("s_waitcnt vmcnt(0)" ::: "memory"); }
    else      { asm volatile("s_waitcnt vmcnt(%0)" :: "n"(NFRW) : "memory"); }
    __builtin_amdgcn_sched_barrier(0);
    __builtin_amdgcn_s_barrier();

    // ---- p3: B(O) all + A(O) m0,1 | stage A(tE2) ----
    RD_B(bO);
    RD_A2(bO, 0);
#pragma unroll
    for (int u = 0; u < 4; ++u) stage_u(tE2, u);
    GATE(); MFMA_BLOCK(0);
    __builtin_amdgcn_s_barrier();

    // ---- p4: A(O) m2,3 | stage B(tO2); confirm tile E2 ----
    RD_A2(bO, 2);
#pragma unroll
    for (int u = 0; u < NFRW; ++u) stage_u(tO2, 4 + u);
    GATE(); MFMA_BLOCK(2);
    if (!last) { asm volatile("s_waitcnt vmcnt(%0)" :: "n"(NFRW) : "memory"); }
    __builtin_amdgcn_sched_barrier(0);
    __builtin_amdgcn_s_barrier();
  }
#undef MFMA_BLOCK
#undef GATE
#undef RD_A2
#undef RD_B

  // ---- epilogue ----
#pragma unroll
  for (int mf = 0; mf < 4; ++mf) {
    const int row0 = bm + wm * 64 + mf * 16 + g * 4;
#pragma unroll
    for (int nf = 0; nf < NFRW; ++nf) {
      const int col = bn + wn * (BN / 2) + nf * 16 + lr;
      if constexpr (MODE == 1) {
#pragma unroll
        for (int r = 0; r < 4; ++r)
          ((float*)C0)[(size_t)(row0 + r) * N + col] = acc[mf][nf][r];
      } else {
        if (col < HID) {
#pragma unroll
          for (int r = 0; r < 4; ++r)
            ((unsigned short*)C0)[(size_t)(row0 + r) * HID + col] = f2b(acc[mf][nf][r]);
        } else if (col < HID + KVW) {
#pragma unroll
          for (int r = 0; r < 4; ++r)
            ((unsigned short*)C1)[(size_t)(row0 + r) * KVW + (col - HID)] = f2b(acc[mf][nf][r]);
        } else {
          const int c2 = col - HID - KVW;
          ushort4 w;
          w.x = f2b(acc[mf][nf][0]); w.y = f2b(acc[mf][nf][1]);
          w.z = f2b(acc[mf][nf][2]); w.w = f2b(acc[mf][nf][3]);
          *(ushort4*)(void*)&((unsigned short*)C2)[(size_t)c2 * S_LEN + row0] = w;
        }
      }
    }
  }
}

// ---------------- flash attention v4 + hidden Wo-cvt (causal, GQA 4:1) ----------------
// DMA-staged double-buffered K/V, one barrier/tile, folded pairing (33 tiles
// per block). NEW: the Wo fp32->bf16 conversion rides inside this kernel
// (attn is latency-bound at 4.6% HBM): each block converts 1 float4/thread
// per kv-tile, software-pipelined one tile ahead (load early, store at next
// tile start) so no waitcnt stall. 512 blocks x 33 tiles x 256 thr = 4.33M
// slots cover the 4.19M float4 of Wo bijectively.
__global__ __launch_bounds__(256) void attn_kernel(
    const unsigned short* __restrict__ Q, const unsigned short* __restrict__ K,
    const unsigned short* __restrict__ VtG, unsigned short* __restrict__ O,
    const float* __restrict__ WoF, unsigned short* __restrict__ WoB) {
  __shared__ char KlB[2][16384];
  __shared__ char VtB2[2][16384];
  __shared__ unsigned short Pl[4][16][72];

  const int tid  = threadIdx.x;
  const int lane = tid & 63;
  const int wave = tid >> 6;
  const int h    = blockIdx.y;
  const int kvh  = h >> 2;
  const int pair = blockIdx.x;             // [0,16)
  const int lr   = lane & 15;
  const int g    = lane >> 4;
  const int lk8  = g * 8;
  const float scale = 0.08838834764831845f;  // 1/sqrt(128)
  const int blkl = h * 16 + pair;            // [0,512)
  const int CVT_LIM = (HID * HID) / 4;       // float4 count of Wo
  int itg = 0;
  int pendidx = 0x7FFFFFFF;
  float4 pend;

  auto stageK = [&](int kv0, int buf) {
#pragma unroll
    for (int j = 0; j < 4; ++j) {
      const int row  = j * 16 + (tid >> 4);
      const int colb = ((tid & 15) << 4) ^ ((row & 15) << 4);
      const char* src =
          (const char*)(K + (size_t)(kv0 + row) * KVW + (size_t)kvh * HD) + colb;
      gld_lds16(src, &KlB[buf][row * 256 + ((tid & 15) << 4)]);
    }
  };
  auto stageV = [&](int kv0, int buf) {
#pragma unroll
    for (int j = 0; j < 4; ++j) {
      const int row  = j * 32 + (tid >> 3);
      const int colb = ((tid & 7) << 4) ^ ((row & 7) << 4);
      const char* src =
          (const char*)(VtG + ((size_t)kvh * HD + row) * S_LEN + kv0) + colb;
      gld_lds16(src, &VtB2[buf][row * 128 + ((tid & 7) << 4)]);
    }
  };
  auto rdK = [&](int buf, int n, int c) {
    const int row = n * 16 + lr;
    return *(const bf16x8_t*)&KlB[buf][row * 256 +
                                       ((c * 64 + g * 16) ^ ((lr & 15) << 4))];
  };
  auto rdV = [&](int buf, int c, int half) {
    const int row = c * 16 + lr;
    return *(const bf16x8_t*)&VtB2[buf][row * 128 +
                                        ((half * 64 + g * 16) ^ ((lr & 7) << 4))];
  };

  for (int pass = 0; pass < 2; ++pass) {
    const int qb = pass == 0 ? (31 - pair) : pair;
    const int q0 = qb * 64;
    const int qrow = q0 + wave * 16;
    const int nkv = qb + 1;

    bf16x8_t qf[4];
    {
      const unsigned short* qp = Q + (size_t)(qrow + lr) * HID + (size_t)h * HD;
#pragma unroll
      for (int c = 0; c < 4; ++c)
        qf[c] = *(const bf16x8_t*)(const void*)(qp + c * 32 + lk8);
    }
    f32x4_t oacc[8];
#pragma unroll
    for (int c = 0; c < 8; ++c) oacc[c] = f32x4_t{0.f, 0.f, 0.f, 0.f};
    float m_run = -3e38f, l_run = 0.f;

    stageK(0, 0); stageV(0, 0);
    asm volatile("s_waitcnt vmcnt(0)" ::: "memory");
    __builtin_amdgcn_sched_barrier(0);
    __builtin_amdgcn_s_barrier();

    for (int it = 0; it < nkv; ++it) {
      const int kv0 = it * 64;
      const int buf = it & 1;

      // ---- hidden Wo-cvt: flush previous, issue next load (oldest VMEM) ----
      if (pendidx < CVT_LIM) {
        ushort4 o;
        o.x = f2b(pend.x); o.y = f2b(pend.y);
        o.z = f2b(pend.z); o.w = f2b(pend.w);
        reinterpret_cast<ushort4*>(WoB)[pendidx] = o;
      }
      pendidx = (blkl * 33 + itg) * 256 + tid;
      ++itg;
      if (pendidx < CVT_LIM)
        pend = reinterpret_cast<const float4*>(WoF)[pendidx];

      // issue next tile's DMAs (target buf^1: read-complete since end of it-1)
      if (it + 1 < nkv) { stageK(kv0 + 64, buf ^ 1); stageV(kv0 + 64, buf ^ 1); }

      // ---- S^T = K * Q^T ----
      f32x4_t sacc[4];
#pragma unroll
      for (int n = 0; n < 4; ++n) sacc[n] = f32x4_t{0.f, 0.f, 0.f, 0.f};
#pragma unroll
      for (int c = 0; c < 4; ++c) {
        bf16x8_t qc = qf[c];
#pragma unroll
        for (int n = 0; n < 4; ++n)
          sacc[n] = __builtin_amdgcn_mfma_f32_16x16x32_bf16(rdK(buf, n, c), qc,
                                                            sacc[n], 0, 0, 0);
      }

      // ---- softmax over k ----
      const int qg = qrow + lr;
      const bool diag = (it == nkv - 1);
      float p[16];
      float mloc = -3e38f;
#pragma unroll
      for (int n = 0; n < 4; ++n)
#pragma unroll
        for (int r = 0; r < 4; ++r) {
          float x = sacc[n][r] * scale;
          if (diag) {
            int kg = kv0 + n * 16 + g * 4 + r;
            if (kg > qg) x = -3e38f;
          }
          p[n * 4 + r] = x;
          mloc = fmaxf(mloc, x);
        }
      mloc = fmaxf(mloc, __shfl_xor(mloc, 16));
      mloc = fmaxf(mloc, __shfl_xor(mloc, 32));

      if (__any(mloc > m_run + 8.f)) {
        float m_new = fmaxf(m_run, mloc);
        float alpha = __expf(m_run - m_new);
        float a4[4];
#pragma unroll
        for (int r = 0; r < 4; ++r) a4[r] = __shfl(alpha, g * 4 + r);
#pragma unroll
        for (int c = 0; c < 8; ++c)
#pragma unroll
          for (int r = 0; r < 4; ++r) oacc[c][r] *= a4[r];
        l_run *= alpha;
        m_run = m_new;
      }

      float ssum = 0.f;
#pragma unroll
      for (int i = 0; i < 16; ++i) {
        float e = __expf(p[i] - m_run);
        p[i] = e;
        ssum += e;
      }
      ssum += __shfl_xor(ssum, 16);
      ssum += __shfl_xor(ssum, 32);
      l_run += ssum;

#pragma unroll
      for (int n = 0; n < 4; ++n) {
        ushort4 w;
        w.x = f2b(p[n * 4 + 0]); w.y = f2b(p[n * 4 + 1]);
        w.z = f2b(p[n * 4 + 2]); w.w = f2b(p[n * 4 + 3]);
        *(ushort4*)(void*)&Pl[wave][lr][n * 16 + g * 4] = w;
      }

      // ---- PV ----
#pragma unroll
      for (int half = 0; half < 2; ++half) {
        bf16x8_t pf = *(const bf16x8_t*)(const void*)&Pl[wave][lr][half * 32 + lk8];
#pragma unroll
        for (int c = 0; c < 8; ++c)
          oacc[c] = __builtin_amdgcn_mfma_f32_16x16x32_bf16(pf, rdV(buf, c, half),
                                                            oacc[c], 0, 0, 0);
      }

      if (it + 1 < nkv) { asm volatile("s_waitcnt vmcnt(0)" ::: "memory"); }
      __builtin_amdgcn_sched_barrier(0);
      __builtin_amdgcn_s_barrier();
    }

    float linv[4];
#pragma unroll
    for (int r = 0; r < 4; ++r) linv[r] = 1.f / __shfl(l_run, g * 4 + r);
#pragma unroll
    for (int r = 0; r < 4; ++r) {
      int row = qrow + g * 4 + r;
#pragma unroll
      for (int c = 0; c < 8; ++c)
        O[(size_t)row * HID + (size_t)h * HD + c * 16 + lr] = f2b(oacc[c][r] * linv[r]);
    }
  }

  // final pending cvt flush
  if (pendidx < CVT_LIM) {
    ushort4 o;
    o.x = f2b(pend.x); o.y = f2b(pend.y);
    o.z = f2b(pend.z); o.w = f2b(pend.w);
    reinterpret_cast<ushort4*>(WoB)[pendidx] = o;
  }
}

// ---------------- host launch ----------------
extern "C" void kernel_launch(void* const* d_in, const int* in_sizes, int n_in,
                              void* d_out, int out_size, void* d_ws, size_t ws_size,
                              hipStream_t stream) {
  (void)in_sizes; (void)n_in; (void)out_size; (void)ws_size;
  const float* X  = (const float*)d_in[0];
  const float* Wq = (const float*)d_in[1];
  const float* Wk = (const float*)d_in[2];
  const float* Wv = (const float*)d_in[3];
  const float* Wo = (const float*)d_in[4];
  const int*  pos = (const int*)d_in[5];
  float* out = (float*)d_out;

  unsigned short* Xb  = (unsigned short*)d_ws;
  unsigned short* Wqb = Xb  + (size_t)S_LEN * HID;
  unsigned short* Wkb = Wqb + (size_t)HID * HID;    // contiguous with Wqb
  unsigned short* Wvb = Wkb + (size_t)KVW * HID;    // contiguous -> [6144 x 4096] B
  unsigned short* Wob = Wvb + (size_t)KVW * HID;
  unsigned short* Qb  = Wob + (size_t)HID * HID;
  unsigned short* Kb  = Qb  + (size_t)S_LEN * HID;
  unsigned short* VtB = Kb  + (size_t)S_LEN * KVW;  // V^T: [KVW][S_LEN]
  unsigned short* AOb = VtB + (size_t)S_LEN * KVW;

  auto cvt = [&](const float* s, unsigned short* d, size_t n) {
    int n4 = (int)(n / 4);
    int grid = (n4 + 255) / 256;
    if (grid > 4096) grid = 4096;
    cvt_kernel<<<grid, 256, 0, stream>>>(s, d, n4);
  };
  cvt(X,  Xb,  (size_t)S_LEN * HID);
  cvt(Wq, Wqb, (size_t)HID * HID);
  cvt(Wk, Wkb, (size_t)KVW * HID);
  cvt(Wv, Wvb, (size_t)KVW * HID);
  // Wo cvt is hidden inside attn_kernel

  // QKV projection: 128x192 tiles, 4-wave blocks, grid 32x16 = 512 (2/CU)
  gemm4w_kernel<192, 2><<<dim3(QKVN / 192, S_LEN / 128), 256, 0, stream>>>(
      Xb, Wqb, Qb, Kb, VtB, QKVN, HID);

  rope_kernel<<<2048, 256, 0, stream>>>(Qb, Kb, pos);

  // folded-balance attention (+ hidden Wo cvt): 16 pair-blocks x 32 heads
  attn_kernel<<<dim3(16, NH), 256, 0, stream>>>(Qb, Kb, VtB, AOb, Wo, Wob);

  // output projection: 128x128 tiles, 4-wave blocks, grid 32x16 = 512 -> fp32
  gemm4w_kernel<128, 1><<<dim3(HID / 128, S_LEN / 128), 256, 0, stream>>>(
      AOb, Wob, out, nullptr, nullptr, HID, HID);
}